// Round 2
// baseline (134.625 us; speedup 1.0000x reference)
//
#include <hip/hip_runtime.h>
#include <math.h>

#define B 1024
#define E 256
#define H 4
#define DH 64
#define L 192
#define NF 16384
#define NO 49152

// ---------------------------------------------------------------------------
// Kernel 1: per-batch start offsets via binary search (batch arrays sorted).
// ---------------------------------------------------------------------------
__global__ __launch_bounds__(256) void starts_kernel(
    const int* __restrict__ fb, const int* __restrict__ ob,
    int* __restrict__ start_f, int* __restrict__ start_o)
{
  int b = blockIdx.x * 256 + threadIdx.x;
  if (b > B) return;
  int lo = 0, hi = NF;
  while (lo < hi) { int m = (lo + hi) >> 1; if (fb[m] < b) lo = m + 1; else hi = m; }
  start_f[b] = lo;
  lo = 0; hi = NO;
  while (lo < hi) { int m = (lo + hi) >> 1; if (ob[m] < b) lo = m + 1; else hi = m; }
  start_o[b] = lo;
}

// ---------------------------------------------------------------------------
// Kernel 2: fully fused per-batch pipeline. One block (4 waves) per batch.
//   q = scene@Wq^T + bq
//   Y[h,:] = q_h @ Wk_h          (K-projection folded into q-direction)
//   scores[h,l] = (X[l]·Y[h] + q_h·bk_h) / 8
//   softmax -> attnw
//   Z[h,:] = sum_l attn[h,l] X[l]  (V-projection folded: ctx = Wv_h@Z_h + bv)
//   out-proj + residual + LayerNorm
// Scratch: none beyond LDS. ws only holds the 8KB start arrays.
// ---------------------------------------------------------------------------
__global__ __launch_bounds__(256) void fused_kernel(
    const float* __restrict__ scene,
    const float* __restrict__ face, const float* __restrict__ obj,
    const float* __restrict__ ipw, const float* __restrict__ ipb,
    const float* __restrict__ opw, const float* __restrict__ opb,
    const float* __restrict__ gamma, const float* __restrict__ beta,
    const int* __restrict__ start_f, const int* __restrict__ start_o,
    float* __restrict__ fused, float* __restrict__ attnw)
{
  int b = blockIdx.x, t = threadIdx.x;
  int wave = t >> 6, lane = t & 63;

  __shared__ float sf_s[E], q_s[E], ctx_s[E];
  __shared__ float Y_s[H][E];
  __shared__ float Z_s[H][E];
  __shared__ float s_s[H][L];
  __shared__ float sb_s[H];
  __shared__ float red_s[8];

  sf_s[t] = scene[(size_t)b * E + t];
  __syncthreads();

  // ---- Q projection: thread t -> q[t] (row-dot against L2-hot Wq) ----
  {
    const float* wrow = ipw + (size_t)t * E;
    float acc = ipb[t];
#pragma unroll 8
    for (int j = 0; j < E; j += 4) {
      float4 w4 = *(const float4*)(wrow + j);
      acc += sf_s[j] * w4.x + sf_s[j+1] * w4.y + sf_s[j+2] * w4.z + sf_s[j+3] * w4.w;
    }
    q_s[t] = acc;
  }
  __syncthreads();

  // ---- Y[h][e=t] = sum_d q[h*64+d] * Wk[h*64+d][e]  (coalesced over t) ----
  {
    const float* Wk = ipw + (size_t)E * E;
    float y[H];
#pragma unroll
    for (int h = 0; h < H; ++h) {
      const float* wc = Wk + (size_t)h * DH * E + t;
      float acc = 0.f;
#pragma unroll 8
      for (int d = 0; d < DH; ++d)
        acc += q_s[h * DH + d] * wc[(size_t)d * E];   // q_s: LDS broadcast
      y[h] = acc;
    }
#pragma unroll
    for (int h = 0; h < H; ++h) Y_s[h][t] = y[h];
  }
  // ---- score bias sb[h] = q_h · bk_h  (wave h reduces) ----
  {
    float v = q_s[wave * DH + lane] * ipb[E + wave * DH + lane];
#pragma unroll
    for (int o = 32; o; o >>= 1) v += __shfl_xor(v, o);
    if (lane == 0) sb_s[wave] = v;
  }

  int sf0 = start_f[b], cf = start_f[b + 1] - sf0;
  int so0 = start_o[b], co = start_o[b + 1] - so0;
  int n_f = min(cf, L);              // faces occupy slots 0..n_f-1
  int n   = min(cf + co, L);         // total kept slots (ref drops pos>=L)

  __syncthreads();

  if (n > 0) {
    // ---- scores: wave handles node s, lanes split the E dim ----
    for (int s = wave; s < n; s += H) {
      const float* xrow = (s < n_f) ? face + (size_t)(sf0 + s) * E
                                    : obj  + (size_t)(so0 + s - n_f) * E;
      float4 x4 = ((const float4*)xrow)[lane];
      float4 y0 = *(const float4*)&Y_s[0][lane * 4];
      float4 y1 = *(const float4*)&Y_s[1][lane * 4];
      float4 y2 = *(const float4*)&Y_s[2][lane * 4];
      float4 y3 = *(const float4*)&Y_s[3][lane * 4];
      float p0 = x4.x*y0.x + x4.y*y0.y + x4.z*y0.z + x4.w*y0.w;
      float p1 = x4.x*y1.x + x4.y*y1.y + x4.z*y1.z + x4.w*y1.w;
      float p2 = x4.x*y2.x + x4.y*y2.y + x4.z*y2.z + x4.w*y2.w;
      float p3 = x4.x*y3.x + x4.y*y3.y + x4.z*y3.z + x4.w*y3.w;
#pragma unroll
      for (int o = 32; o; o >>= 1) {
        p0 += __shfl_xor(p0, o); p1 += __shfl_xor(p1, o);
        p2 += __shfl_xor(p2, o); p3 += __shfl_xor(p3, o);
      }
      if (lane == 0) {
        s_s[0][s] = (p0 + sb_s[0]) * 0.125f;
        s_s[1][s] = (p1 + sb_s[1]) * 0.125f;
        s_s[2][s] = (p2 + sb_s[2]) * 0.125f;
        s_s[3][s] = (p3 + sb_s[3]) * 0.125f;
      }
    }
    __syncthreads();

    // ---- softmax: wave h owns head h ----
    {
      float m = -3.0e38f;
      for (int s = lane; s < n; s += 64) m = fmaxf(m, s_s[wave][s]);
#pragma unroll
      for (int o = 32; o; o >>= 1) m = fmaxf(m, __shfl_xor(m, o));
      float sum = 0.f;
      for (int s = lane; s < n; s += 64) {
        float e = __expf(s_s[wave][s] - m);
        s_s[wave][s] = e;
        sum += e;
      }
#pragma unroll
      for (int o = 32; o; o >>= 1) sum += __shfl_xor(sum, o);
      float inv = 1.0f / sum;
      for (int s = lane; s < n; s += 64) s_s[wave][s] *= inv;
    }
    __syncthreads();

    // attnw: mean over heads; masked slots exactly 0 (matches exp underflow)
    if (t < L) {
      float v = (t < n) ? 0.25f * (s_s[0][t] + s_s[1][t] + s_s[2][t] + s_s[3][t]) : 0.f;
      attnw[(size_t)b * L + t] = v;
    }

    // ---- Z[h][e=t] = sum_l attn[h,l] * X[l,e]  (coalesced; rows L1/L2-hot) ----
    {
      float z0 = 0.f, z1 = 0.f, z2 = 0.f, z3 = 0.f;
      for (int s = 0; s < n; ++s) {
        const float* xrow = (s < n_f) ? face + (size_t)(sf0 + s) * E
                                      : obj  + (size_t)(so0 + s - n_f) * E;
        float xv = xrow[t];
        z0 += s_s[0][s] * xv; z1 += s_s[1][s] * xv;
        z2 += s_s[2][s] * xv; z3 += s_s[3][s] * xv;
      }
      Z_s[0][t] = z0; Z_s[1][t] = z1; Z_s[2][t] = z2; Z_s[3][t] = z3;
    }
    __syncthreads();

    // ---- ctx[t] = Wv[t,:] · Z[head(t),:] + bv[t]   (sum over heads is Σattn=1) ----
    {
      const float* wvrow = ipw + (size_t)2 * E * E + (size_t)t * E;
      const float* zr = Z_s[t >> 6];
      float acc = ipb[2 * E + t];
#pragma unroll 8
      for (int j = 0; j < E; j += 4) {
        float4 w4 = *(const float4*)(wvrow + j);
        acc += zr[j] * w4.x + zr[j+1] * w4.y + zr[j+2] * w4.z + zr[j+3] * w4.w;
      }
      ctx_s[t] = acc;
    }
  } else {
    // empty batch: softmax over all-NEG row uniform; all V rows = bv
    if (t < L) attnw[(size_t)b * L + t] = 1.0f / L;
    ctx_s[t] = ipb[2 * E + t];
  }
  __syncthreads();

  // ---- out proj + residual + LayerNorm ----
  float x;
  {
    const float* wrow = opw + (size_t)t * E;
    float acc = opb[t];
#pragma unroll 8
    for (int j = 0; j < E; j += 4) {
      float4 w4 = *(const float4*)(wrow + j);
      acc += ctx_s[j] * w4.x + ctx_s[j+1] * w4.y + ctx_s[j+2] * w4.z + ctx_s[j+3] * w4.w;
    }
    x = sf_s[t] + acc;
  }
  float s1 = x;
#pragma unroll
  for (int o = 32; o; o >>= 1) s1 += __shfl_xor(s1, o);
  if (lane == 0) red_s[wave] = s1;
  __syncthreads();
  float mu = (red_s[0] + red_s[1] + red_s[2] + red_s[3]) * (1.0f / E);
  float dx = x - mu;
  float s2 = dx * dx;
#pragma unroll
  for (int o = 32; o; o >>= 1) s2 += __shfl_xor(s2, o);
  if (lane == 0) red_s[4 + wave] = s2;
  __syncthreads();
  float var = (red_s[4] + red_s[5] + red_s[6] + red_s[7]) * (1.0f / E);
  float y = dx * (1.0f / sqrtf(var + 1e-5f)) * gamma[t] + beta[t];
  fused[(size_t)b * E + t] = y;
}

// ---------------------------------------------------------------------------
extern "C" void kernel_launch(void* const* d_in, const int* in_sizes, int n_in,
                              void* d_out, int out_size, void* d_ws, size_t ws_size,
                              hipStream_t stream) {
  const float* scene = (const float*)d_in[0];
  const float* face  = (const float*)d_in[1];
  const float* obj   = (const float*)d_in[2];
  const int*   fb    = (const int*)d_in[3];
  const int*   ob    = (const int*)d_in[4];
  const float* ipw   = (const float*)d_in[5];
  const float* ipb   = (const float*)d_in[6];
  const float* opw   = (const float*)d_in[7];
  const float* opb   = (const float*)d_in[8];
  const float* gam   = (const float*)d_in[9];
  const float* bet   = (const float*)d_in[10];

  float* fused = (float*)d_out;
  float* attnw = fused + (size_t)B * E;

  int* start_f = (int*)d_ws;             // B+1 ints
  int* start_o = start_f + (B + 1);      // B+1 ints  (total ~8.2 KB of ws)

  starts_kernel<<<(B + 1 + 255) / 256, 256, 0, stream>>>(fb, ob, start_f, start_o);
  fused_kernel<<<B, 256, 0, stream>>>(scene, face, obj, ipw, ipb, opw, opb,
                                      gam, bet, start_f, start_o, fused, attnw);
}

// Round 4
// 83.017 us; speedup vs baseline: 1.6217x; 1.6217x over previous
//
#include <hip/hip_runtime.h>
#include <math.h>

#define B 1024
#define E 256
#define H 4
#define DH 64
#define L 192
#define NF 16384
#define NO 49152

// ---------------------------------------------------------------------------
// Kernel 1: per-batch start offsets via binary search (batch arrays sorted).
// ---------------------------------------------------------------------------
__global__ __launch_bounds__(256) void starts_kernel(
    const int* __restrict__ fb, const int* __restrict__ ob,
    int* __restrict__ start_f, int* __restrict__ start_o)
{
  int b = blockIdx.x * 256 + threadIdx.x;
  if (b > B) return;
  int lo = 0, hi = NF;
  while (lo < hi) { int m = (lo + hi) >> 1; if (fb[m] < b) lo = m + 1; else hi = m; }
  start_f[b] = lo;
  lo = 0; hi = NO;
  while (lo < hi) { int m = (lo + hi) >> 1; if (ob[m] < b) lo = m + 1; else hi = m; }
  start_o[b] = lo;
}

// ---------------------------------------------------------------------------
// Kernel 2: q = scene@Wq^T+bq ; Y[b,h,:] = q_h @ Wk_h ; sb[b,h] = q_h·bk_h.
// 4 batches per block, 256 blocks. Weights stream through L2 (hot).
// ---------------------------------------------------------------------------
__global__ __launch_bounds__(256) void qy_kernel(
    const float* __restrict__ scene,
    const float* __restrict__ ipw, const float* __restrict__ ipb,
    float* __restrict__ Yws, float* __restrict__ sbws)
{
  int b0 = blockIdx.x * 4;
  int t = threadIdx.x;

  __shared__ float sc_s[4][E];
  __shared__ float q_s[4][E];

  // stage 4 scene rows
  for (int i = t; i < 4 * E; i += 256)
    ((float*)sc_s)[i] = scene[(size_t)b0 * E + i];
  __syncthreads();

  // q[b][t] for b=0..3 (Wq row t per thread; L2-hot)
  {
    const float* wrow = ipw + (size_t)t * E;
    float a0 = ipb[t], a1 = a0, a2 = a0, a3 = a0;
#pragma unroll 8
    for (int j = 0; j < E; j += 4) {
      float4 w4 = *(const float4*)(wrow + j);
      a0 += sc_s[0][j]*w4.x + sc_s[0][j+1]*w4.y + sc_s[0][j+2]*w4.z + sc_s[0][j+3]*w4.w;
      a1 += sc_s[1][j]*w4.x + sc_s[1][j+1]*w4.y + sc_s[1][j+2]*w4.z + sc_s[1][j+3]*w4.w;
      a2 += sc_s[2][j]*w4.x + sc_s[2][j+1]*w4.y + sc_s[2][j+2]*w4.z + sc_s[2][j+3]*w4.w;
      a3 += sc_s[3][j]*w4.x + sc_s[3][j+1]*w4.y + sc_s[3][j+2]*w4.z + sc_s[3][j+3]*w4.w;
    }
    q_s[0][t] = a0; q_s[1][t] = a1; q_s[2][t] = a2; q_s[3][t] = a3;
  }
  __syncthreads();

  // sb[b][h] = q_h · bk_h  (16 threads, tiny)
  if (t < 16) {
    int b = t >> 2, h = t & 3;
    float acc = 0.f;
#pragma unroll 8
    for (int d = 0; d < DH; ++d)
      acc += q_s[b][h * DH + d] * ipb[E + h * DH + d];
    sbws[(size_t)(b0 + b) * H + h] = acc;
  }

  // Y[b][h][e=t] = sum_d q[b][h*64+d] * Wk[h*64+d][e]  (coalesced over t)
  {
    const float* Wk = ipw + (size_t)E * E;
    float acc[4][4] = {};
#pragma unroll
    for (int h = 0; h < H; ++h) {
      for (int d = 0; d < DH; ++d) {
        float w = Wk[(size_t)(h * DH + d) * E + t];
#pragma unroll
        for (int b = 0; b < 4; ++b)
          acc[b][h] += q_s[b][h * DH + d] * w;
      }
    }
#pragma unroll
    for (int b = 0; b < 4; ++b)
#pragma unroll
      for (int h = 0; h < H; ++h)
        Yws[(size_t)(b0 + b) * (H * E) + h * E + t] = acc[b][h];
  }
}

// ---------------------------------------------------------------------------
// Kernel 3: per-batch X-stream: scores = X·Y + sb, softmax, attnw, Z = attn@X.
// One block (4 waves) per batch. No weight traffic.
// ---------------------------------------------------------------------------
__global__ __launch_bounds__(256) void stream_kernel(
    const float* __restrict__ face, const float* __restrict__ obj,
    const float* __restrict__ Yws, const float* __restrict__ sbws,
    const int* __restrict__ start_f, const int* __restrict__ start_o,
    float* __restrict__ Zws, float* __restrict__ attnw)
{
  int b = blockIdx.x, t = threadIdx.x;
  int wave = t >> 6, lane = t & 63;
  int g = lane >> 4, sl = lane & 15;       // 16-lane groups, 16 groups total
  int gid = wave * 4 + g;

  __shared__ float Y_s[H][E];
  __shared__ float s_s[H][L];
  __shared__ float Zp_s[4][H][E];          // per-wave Z partials (16 KB)
  __shared__ float sb_s[H];

  int sf0 = start_f[b], cf = start_f[b + 1] - sf0;
  int so0 = start_o[b], co = start_o[b + 1] - so0;
  int n_f = min(cf, L);
  int n   = min(cf + co, L);

  if (n == 0) {
    if (t < L) attnw[(size_t)b * L + t] = 1.0f / L;
#pragma unroll
    for (int h = 0; h < H; ++h)
      Zws[(size_t)b * (H * E) + h * E + t] = 0.f;
    return;
  }

  for (int i = t; i < H * E; i += 256)
    ((float*)Y_s)[i] = Yws[(size_t)b * (H * E) + i];
  if (t < H) sb_s[t] = sbws[(size_t)b * H + t];
  __syncthreads();

  // ---- scores: 16 groups × 16 lanes; group owns row s, lanes split E ----
  for (int s = gid; s < n; s += 16) {
    const float* xrow = (s < n_f) ? face + (size_t)(sf0 + s) * E
                                  : obj  + (size_t)(so0 + s - n_f) * E;
    const float4* xr = (const float4*)xrow;
    float p0 = 0.f, p1 = 0.f, p2 = 0.f, p3 = 0.f;
#pragma unroll
    for (int k = 0; k < 4; ++k) {
      float4 x4 = xr[sl + 16 * k];
      int d = 4 * sl + 64 * k;
      float4 y0 = *(const float4*)&Y_s[0][d];
      float4 y1 = *(const float4*)&Y_s[1][d];
      float4 y2 = *(const float4*)&Y_s[2][d];
      float4 y3 = *(const float4*)&Y_s[3][d];
      p0 += x4.x*y0.x + x4.y*y0.y + x4.z*y0.z + x4.w*y0.w;
      p1 += x4.x*y1.x + x4.y*y1.y + x4.z*y1.z + x4.w*y1.w;
      p2 += x4.x*y2.x + x4.y*y2.y + x4.z*y2.z + x4.w*y2.w;
      p3 += x4.x*y3.x + x4.y*y3.y + x4.z*y3.z + x4.w*y3.w;
    }
#pragma unroll
    for (int o = 8; o; o >>= 1) {          // reduce within 16-lane group
      p0 += __shfl_xor(p0, o); p1 += __shfl_xor(p1, o);
      p2 += __shfl_xor(p2, o); p3 += __shfl_xor(p3, o);
    }
    if (sl == 0) {
      s_s[0][s] = (p0 + sb_s[0]) * 0.125f;
      s_s[1][s] = (p1 + sb_s[1]) * 0.125f;
      s_s[2][s] = (p2 + sb_s[2]) * 0.125f;
      s_s[3][s] = (p3 + sb_s[3]) * 0.125f;
    }
  }
  __syncthreads();

  // ---- softmax: wave h owns head h ----
  {
    float m = -3.0e38f;
    for (int s = lane; s < n; s += 64) m = fmaxf(m, s_s[wave][s]);
#pragma unroll
    for (int o = 32; o; o >>= 1) m = fmaxf(m, __shfl_xor(m, o));
    float sum = 0.f;
    for (int s = lane; s < n; s += 64) {
      float e = __expf(s_s[wave][s] - m);
      s_s[wave][s] = e;
      sum += e;
    }
#pragma unroll
    for (int o = 32; o; o >>= 1) sum += __shfl_xor(sum, o);
    float inv = 1.0f / sum;
    for (int s = lane; s < n; s += 64) s_s[wave][s] *= inv;
  }
  __syncthreads();

  if (t < L) {
    float v = (t < n) ? 0.25f * (s_s[0][t] + s_s[1][t] + s_s[2][t] + s_s[3][t]) : 0.f;
    attnw[(size_t)b * L + t] = v;
  }

  // ---- Z: wave w takes rows s = w, w+4, ... ; 16 accums (4e x 4h) ----
  {
    float acc[4][4] = {};                  // [j in float4][h]
    for (int s = wave; s < n; s += 4) {
      const float* xrow = (s < n_f) ? face + (size_t)(sf0 + s) * E
                                    : obj  + (size_t)(so0 + s - n_f) * E;
      float4 x4 = ((const float4*)xrow)[lane];
      float a0 = s_s[0][s], a1 = s_s[1][s], a2 = s_s[2][s], a3 = s_s[3][s];
      acc[0][0] += a0*x4.x; acc[1][0] += a0*x4.y; acc[2][0] += a0*x4.z; acc[3][0] += a0*x4.w;
      acc[0][1] += a1*x4.x; acc[1][1] += a1*x4.y; acc[2][1] += a1*x4.z; acc[3][1] += a1*x4.w;
      acc[0][2] += a2*x4.x; acc[1][2] += a2*x4.y; acc[2][2] += a2*x4.z; acc[3][2] += a2*x4.w;
      acc[0][3] += a3*x4.x; acc[1][3] += a3*x4.y; acc[2][3] += a3*x4.z; acc[3][3] += a3*x4.w;
    }
#pragma unroll
    for (int h = 0; h < H; ++h) {
      float4 v = make_float4(acc[0][h], acc[1][h], acc[2][h], acc[3][h]);
      *(float4*)&Zp_s[wave][h][4 * lane] = v;
    }
  }
  __syncthreads();

  // combine partials and store Z
#pragma unroll
  for (int h = 0; h < H; ++h) {
    float z = Zp_s[0][h][t] + Zp_s[1][h][t] + Zp_s[2][h][t] + Zp_s[3][h][t];
    Zws[(size_t)b * (H * E) + h * E + t] = z;
  }
}

// ---------------------------------------------------------------------------
// Kernel 4: ctx = Wv_h @ Z_h + bv ; out-proj + residual + LayerNorm.
// 4 batches per block, 256 blocks.
// ---------------------------------------------------------------------------
__global__ __launch_bounds__(256) void out_kernel(
    const float* __restrict__ scene, const float* __restrict__ Zws,
    const float* __restrict__ ipw, const float* __restrict__ ipb,
    const float* __restrict__ opw, const float* __restrict__ opb,
    const float* __restrict__ gamma, const float* __restrict__ beta,
    float* __restrict__ fused)
{
  int b0 = blockIdx.x * 4;
  int t = threadIdx.x;
  int wave = t >> 6, lane = t & 63;

  __shared__ float Z_s[4][H * E];          // 16 KB
  __shared__ float ctx_s[4][E];
  __shared__ float x_s[4][E];

  for (int i = t; i < 4 * H * E; i += 256)
    ((float*)Z_s)[i] = Zws[(size_t)b0 * (H * E) + i];
  __syncthreads();

  // ctx[b][o=t] = bv[o] + Wv[o,:] · Z[b][h(o)][:]
  {
    int h = t >> 6;
    const float* wvrow = ipw + (size_t)2 * E * E + (size_t)t * E;
    float base = ipb[2 * E + t];
    float a0 = base, a1 = base, a2 = base, a3 = base;
#pragma unroll 8
    for (int j = 0; j < E; j += 4) {
      float4 w4 = *(const float4*)(wvrow + j);
      const float* z0 = &Z_s[0][h * E + j];
      const float* z1 = &Z_s[1][h * E + j];
      const float* z2 = &Z_s[2][h * E + j];
      const float* z3 = &Z_s[3][h * E + j];
      a0 += z0[0]*w4.x + z0[1]*w4.y + z0[2]*w4.z + z0[3]*w4.w;
      a1 += z1[0]*w4.x + z1[1]*w4.y + z1[2]*w4.z + z1[3]*w4.w;
      a2 += z2[0]*w4.x + z2[1]*w4.y + z2[2]*w4.z + z2[3]*w4.w;
      a3 += z3[0]*w4.x + z3[1]*w4.y + z3[2]*w4.z + z3[3]*w4.w;
    }
    ctx_s[0][t] = a0; ctx_s[1][t] = a1; ctx_s[2][t] = a2; ctx_s[3][t] = a3;
  }
  __syncthreads();

  // x[b][e=t] = scene + out_proj(ctx)
  {
    const float* wrow = opw + (size_t)t * E;
    float base = opb[t];
    float a0 = base, a1 = base, a2 = base, a3 = base;
#pragma unroll 8
    for (int j = 0; j < E; j += 4) {
      float4 w4 = *(const float4*)(wrow + j);
      a0 += ctx_s[0][j]*w4.x + ctx_s[0][j+1]*w4.y + ctx_s[0][j+2]*w4.z + ctx_s[0][j+3]*w4.w;
      a1 += ctx_s[1][j]*w4.x + ctx_s[1][j+1]*w4.y + ctx_s[1][j+2]*w4.z + ctx_s[1][j+3]*w4.w;
      a2 += ctx_s[2][j]*w4.x + ctx_s[2][j+1]*w4.y + ctx_s[2][j+2]*w4.z + ctx_s[2][j+3]*w4.w;
      a3 += ctx_s[3][j]*w4.x + ctx_s[3][j+1]*w4.y + ctx_s[3][j+2]*w4.z + ctx_s[3][j+3]*w4.w;
    }
    x_s[0][t] = a0 + scene[(size_t)(b0 + 0) * E + t];
    x_s[1][t] = a1 + scene[(size_t)(b0 + 1) * E + t];
    x_s[2][t] = a2 + scene[(size_t)(b0 + 2) * E + t];
    x_s[3][t] = a3 + scene[(size_t)(b0 + 3) * E + t];
  }
  __syncthreads();

  // LayerNorm: wave w handles batch b0+w (E=256 over 64 lanes x 4)
  {
    float v0 = x_s[wave][lane], v1 = x_s[wave][lane + 64],
          v2 = x_s[wave][lane + 128], v3 = x_s[wave][lane + 192];
    float s1 = v0 + v1 + v2 + v3;
#pragma unroll
    for (int o = 32; o; o >>= 1) s1 += __shfl_xor(s1, o);
    float mu = s1 * (1.0f / E);
    float d0 = v0 - mu, d1 = v1 - mu, d2 = v2 - mu, d3 = v3 - mu;
    float s2 = d0*d0 + d1*d1 + d2*d2 + d3*d3;
#pragma unroll
    for (int o = 32; o; o >>= 1) s2 += __shfl_xor(s2, o);
    float inv = 1.0f / sqrtf(s2 * (1.0f / E) + 1e-5f);
    size_t base = (size_t)(b0 + wave) * E;
    fused[base + lane      ] = d0 * inv * gamma[lane      ] + beta[lane      ];
    fused[base + lane +  64] = d1 * inv * gamma[lane +  64] + beta[lane +  64];
    fused[base + lane + 128] = d2 * inv * gamma[lane + 128] + beta[lane + 128];
    fused[base + lane + 192] = d3 * inv * gamma[lane + 192] + beta[lane + 192];
  }
}

// ---------------------------------------------------------------------------
extern "C" void kernel_launch(void* const* d_in, const int* in_sizes, int n_in,
                              void* d_out, int out_size, void* d_ws, size_t ws_size,
                              hipStream_t stream) {
  const float* scene = (const float*)d_in[0];
  const float* face  = (const float*)d_in[1];
  const float* obj   = (const float*)d_in[2];
  const int*   fb    = (const int*)d_in[3];
  const int*   ob    = (const int*)d_in[4];
  const float* ipw   = (const float*)d_in[5];
  const float* ipb   = (const float*)d_in[6];
  const float* opw   = (const float*)d_in[7];
  const float* opb   = (const float*)d_in[8];
  const float* gam   = (const float*)d_in[9];
  const float* bet   = (const float*)d_in[10];

  float* fused = (float*)d_out;
  float* attnw = fused + (size_t)B * E;

  // ws layout: starts (8.2KB, padded to 16KB) | Y (4MB) | sb (16KB) | Z (4MB)
  int* start_f = (int*)d_ws;
  int* start_o = start_f + (B + 1);
  float* Yws  = (float*)((char*)d_ws + (16 << 10));
  float* sbws = Yws + (size_t)B * H * E;
  float* Zws  = sbws + (size_t)B * H;
  // total: 16KB + 4MB + 16KB + 4MB ~= 8.4 MB of ws

  starts_kernel<<<(B + 1 + 255) / 256, 256, 0, stream>>>(fb, ob, start_f, start_o);
  qy_kernel<<<B / 4, 256, 0, stream>>>(scene, ipw, ipb, Yws, sbws);
  stream_kernel<<<B, 256, 0, stream>>>(face, obj, Yws, sbws, start_f, start_o, Zws, attnw);
  out_kernel<<<B / 4, 256, 0, stream>>>(scene, Zws, ipw, ipb, opw, opb, gam, bet, fused);
}